// Round 1
// baseline (628.578 us; speedup 1.0000x reference)
//
#include <hip/hip_runtime.h>

#define BLK 256

// ---------------------------------------------------------------------------
// Kernel 1: per-feature sums. acc[f*14 + k]:
//   k=0..3  : sum_b x[b,f,k]
//   k=4..13 : sum_b x_i*x_j in tril order (00,10,11,20,21,22,30,31,32,33)
// ---------------------------------------------------------------------------
__global__ void qbn_stats(const float* __restrict__ x, float* __restrict__ acc,
                          int B, int F, int b_per) {
  int f = blockIdx.x * blockDim.x + threadIdx.x;
  if (f >= F) return;
  int b0 = blockIdx.y * b_per;
  int b1 = min(b0 + b_per, B);

  float s0 = 0.f, s1 = 0.f, s2 = 0.f, s3 = 0.f;
  float q00 = 0.f, q10 = 0.f, q11 = 0.f, q20 = 0.f, q21 = 0.f;
  float q22 = 0.f, q30 = 0.f, q31 = 0.f, q32 = 0.f, q33 = 0.f;

  const float4* xv = (const float4*)x;
  for (int b = b0; b < b1; ++b) {
    float4 v = xv[(size_t)b * F + f];
    s0 += v.x; s1 += v.y; s2 += v.z; s3 += v.w;
    q00 += v.x * v.x;
    q10 += v.y * v.x; q11 += v.y * v.y;
    q20 += v.z * v.x; q21 += v.z * v.y; q22 += v.z * v.z;
    q30 += v.w * v.x; q31 += v.w * v.y; q32 += v.w * v.z; q33 += v.w * v.w;
  }
  float* a = acc + (size_t)f * 14;
  atomicAdd(a + 0, s0);  atomicAdd(a + 1, s1);  atomicAdd(a + 2, s2);  atomicAdd(a + 3, s3);
  atomicAdd(a + 4, q00); atomicAdd(a + 5, q10); atomicAdd(a + 6, q11);
  atomicAdd(a + 7, q20); atomicAdd(a + 8, q21); atomicAdd(a + 9, q22);
  atomicAdd(a + 10, q30); atomicAdd(a + 11, q31); atomicAdd(a + 12, q32); atomicAdd(a + 13, q33);
}

// ---------------------------------------------------------------------------
// Cholesky of (cov + eps*I). Returns false if any pivot is non-positive / NaN
// (the condition under which jnp.linalg.cholesky yields NaN).
// ---------------------------------------------------------------------------
__device__ __forceinline__ bool cholesky4(const float cov[4][4], float eps,
                                          float L[4][4]) {
  float A[4][4];
#pragma unroll
  for (int i = 0; i < 4; ++i)
#pragma unroll
    for (int j = 0; j < 4; ++j) A[i][j] = cov[i][j];
#pragma unroll
  for (int i = 0; i < 4; ++i) A[i][i] += eps;

#pragma unroll
  for (int j = 0; j < 4; ++j) {
    float d = A[j][j];
#pragma unroll
    for (int k = 0; k < 4; ++k)
      if (k < j) d -= L[j][k] * L[j][k];
    if (!(d > 0.0f)) return false;  // catches d<=0 and NaN
    float s = sqrtf(d);
    L[j][j] = s;
    float inv = 1.0f / s;
#pragma unroll
    for (int i = 0; i < 4; ++i) {
      if (i > j) {
        float v = A[i][j];
#pragma unroll
        for (int k = 0; k < 4; ++k)
          if (k < j) v -= L[i][k] * L[j][k];
        L[i][j] = v * inv;
      } else if (i < j) {
        L[i][j] = 0.0f;
      }
    }
  }
  return true;
}

// ---------------------------------------------------------------------------
// Kernel 2: per-feature finalize. Produces Ac[f*20]: A (4x4 row-major) then c,
// where out = A @ x + c  with  A = gamma_sym @ L^-1,  c = beta - A @ mean.
// ---------------------------------------------------------------------------
__global__ void qbn_finalize(const float* __restrict__ acc,
                             const float* __restrict__ gamma,
                             const float* __restrict__ beta,
                             float* __restrict__ Ac, int B, int F) {
  int f = blockIdx.x * blockDim.x + threadIdx.x;
  if (f >= F) return;
  const float* a = acc + (size_t)f * 14;
  float invB = 1.0f / (float)B;
  float m[4] = {a[0] * invB, a[1] * invB, a[2] * invB, a[3] * invB};

  float cov[4][4];
  cov[0][0] = a[4] * invB - m[0] * m[0];
  cov[1][0] = a[5] * invB - m[1] * m[0];
  cov[1][1] = a[6] * invB - m[1] * m[1];
  cov[2][0] = a[7] * invB - m[2] * m[0];
  cov[2][1] = a[8] * invB - m[2] * m[1];
  cov[2][2] = a[9] * invB - m[2] * m[2];
  cov[3][0] = a[10] * invB - m[3] * m[0];
  cov[3][1] = a[11] * invB - m[3] * m[1];
  cov[3][2] = a[12] * invB - m[3] * m[2];
  cov[3][3] = a[13] * invB - m[3] * m[3];
  cov[0][1] = cov[1][0]; cov[0][2] = cov[2][0]; cov[0][3] = cov[3][0];
  cov[1][2] = cov[2][1]; cov[1][3] = cov[3][1]; cov[2][3] = cov[3][2];

  // 3-level fallback exactly as reference
  float L[4][4];
  if (!cholesky4(cov, 1e-5f, L)) {
    if (!cholesky4(cov, 0.1f, L)) {
      float dm = 0.25f * (fabsf(cov[0][0]) + fabsf(cov[1][1]) +
                          fabsf(cov[2][2]) + fabsf(cov[3][3]));
      float scale = sqrtf(fmaxf(dm, 1.0f));
#pragma unroll
      for (int i = 0; i < 4; ++i)
#pragma unroll
        for (int j = 0; j < 4; ++j) L[i][j] = (i == j) ? scale : 0.0f;
    }
  }

  // Invert lower-triangular L (forward substitution vs identity)
  float Li[4][4];
#pragma unroll
  for (int i = 0; i < 4; ++i)
#pragma unroll
    for (int j = 0; j < 4; ++j) Li[i][j] = 0.0f;
#pragma unroll
  for (int j = 0; j < 4; ++j) {
    Li[j][j] = 1.0f / L[j][j];
#pragma unroll
    for (int i = 0; i < 4; ++i) {
      if (i > j) {
        float s = 0.0f;
#pragma unroll
        for (int k = 0; k < 4; ++k)
          if (k >= j && k < i) s += L[i][k] * Li[k][j];
        Li[i][j] = -s / L[i][i];
      }
    }
  }

  // gamma_sym from tril order (0,0),(1,0),(1,1),(2,0),(2,1),(2,2),(3,0),(3,1),(3,2),(3,3)
  const float* g = gamma + (size_t)f * 10;
  float G[4][4];
  G[0][0] = g[0];
  G[1][0] = g[1]; G[0][1] = g[1];
  G[1][1] = g[2];
  G[2][0] = g[3]; G[0][2] = g[3];
  G[2][1] = g[4]; G[1][2] = g[4];
  G[2][2] = g[5];
  G[3][0] = g[6]; G[0][3] = g[6];
  G[3][1] = g[7]; G[1][3] = g[7];
  G[3][2] = g[8]; G[2][3] = g[8];
  G[3][3] = g[9];

  // A = G @ Li
  float A[4][4];
#pragma unroll
  for (int i = 0; i < 4; ++i)
#pragma unroll
    for (int j = 0; j < 4; ++j) {
      float s = 0.0f;
#pragma unroll
      for (int k = 0; k < 4; ++k) s += G[i][k] * Li[k][j];
      A[i][j] = s;
    }

  const float* bt = beta + (size_t)f * 4;
  float c[4];
#pragma unroll
  for (int i = 0; i < 4; ++i)
    c[i] = bt[i] - (A[i][0] * m[0] + A[i][1] * m[1] + A[i][2] * m[2] + A[i][3] * m[3]);

  float* o = Ac + (size_t)f * 20;
#pragma unroll
  for (int i = 0; i < 4; ++i)
#pragma unroll
    for (int j = 0; j < 4; ++j) o[i * 4 + j] = A[i][j];
#pragma unroll
  for (int i = 0; i < 4; ++i) o[16 + i] = c[i];
}

// ---------------------------------------------------------------------------
// Kernel 3: out[b,f,:] = A[f] @ x[b,f,:] + c[f]
// ---------------------------------------------------------------------------
__global__ void qbn_apply(const float* __restrict__ x,
                          const float* __restrict__ Ac,
                          float* __restrict__ out, int B, int F, int b_per) {
  int f = blockIdx.x * blockDim.x + threadIdx.x;
  if (f >= F) return;
  const float4* p = (const float4*)(Ac + (size_t)f * 20);  // 80B stride, 16B aligned
  float4 A0 = p[0], A1 = p[1], A2 = p[2], A3 = p[3], C = p[4];

  int b0 = blockIdx.y * b_per;
  int b1 = min(b0 + b_per, B);
  const float4* xv = (const float4*)x;
  float4* ov = (float4*)out;
  for (int b = b0; b < b1; ++b) {
    size_t idx = (size_t)b * F + f;
    float4 v = xv[idx];
    float4 o;
    o.x = A0.x * v.x + A0.y * v.y + A0.z * v.z + A0.w * v.w + C.x;
    o.y = A1.x * v.x + A1.y * v.y + A1.z * v.z + A1.w * v.w + C.y;
    o.z = A2.x * v.x + A2.y * v.y + A2.z * v.z + A2.w * v.w + C.z;
    o.w = A3.x * v.x + A3.y * v.y + A3.z * v.z + A3.w * v.w + C.w;
    ov[idx] = o;
  }
}

extern "C" void kernel_launch(void* const* d_in, const int* in_sizes, int n_in,
                              void* d_out, int out_size, void* d_ws, size_t ws_size,
                              hipStream_t stream) {
  const float* x = (const float*)d_in[0];
  const float* gamma = (const float*)d_in[1];
  const float* beta = (const float*)d_in[2];
  float* out = (float*)d_out;

  int F = in_sizes[2] / 4;                 // beta is [F,4]
  int B = in_sizes[0] / (F * 4);           // x is [B,F,4]

  float* acc = (float*)d_ws;               // F*14 floats
  float* Ac = acc + (size_t)F * 14;        // F*20 floats (byte offset F*56, 16B-aligned for F mult of 8)

  hipMemsetAsync(d_ws, 0, (size_t)F * 14 * sizeof(float), stream);

  int fblocks = (F + BLK - 1) / BLK;       // 8
  const int NBY = 64;
  int b_per = (B + NBY - 1) / NBY;         // 128

  dim3 grid(fblocks, NBY);
  qbn_stats<<<grid, BLK, 0, stream>>>(x, acc, B, F, b_per);
  qbn_finalize<<<fblocks, BLK, 0, stream>>>(acc, gamma, beta, Ac, B, F);
  qbn_apply<<<grid, BLK, 0, stream>>>(x, Ac, out, B, F, b_per);
}